// Round 1
// baseline (3340.266 us; speedup 1.0000x reference)
//
#include <hip/hip_runtime.h>
#include <hip/hip_bf16.h>

// ---------------------------------------------------------------------------
// myLSTM: LSTM(B=64,T=512,D=256,H=256) + single-head attn (only t=0 query is
// consumed by the head) + MLP head.
//
// R1 redesign of the scan: ring-of-2 exchange with register-resident Wh.
//   prep_x      : x fp32 -> bf16
//   prep_wit    : fp32 [256,1024] -> bf16 transposed [1024,256] (used for BOTH
//                 Wi->WiT and Wh->WhT; WhT lives in the dead xbf region)
//   init_hx     : tag dwords := 0xFFFFFFFF
//   xg_gemm     : xg = x@Wi + b, written PERMUTED as [gate][u][b][t] so the
//                 scan reads per-lane 2B streams that stay L2-resident and the
//                 epilogue writes 32B-contiguous t-runs.
//   lstm_scan   : 8 persistent WGs = 4 batch-groups(16) x 2 unit-halves(128).
//                 512 threads/WG; each wave owns 64 gate-cols whose Wh
//                 B-fragments are PRE-LOADED INTO 128 VGPRs (no LDS for B).
//                 Per step: own-k-half MFMA -> poll partner h_{t-1} (tagged 8B
//                 agent-scope words, in flight since partner's previous store)
//                 -> barrier -> partner-k-half MFMA -> gates (c in registers,
//                 acc tiles gate-aligned) -> h store (LDS dbuf + fabric+hout)
//                 -> barrier. Only ONE partner => no 16-way lockstep tail.
//   attn_qu/attn_sm/head : unchanged.
// ---------------------------------------------------------------------------

typedef __attribute__((ext_vector_type(8))) short short8;   // 8 x bf16 (4 VGPR)
typedef __attribute__((ext_vector_type(4))) float float4v;  // MFMA acc

__device__ __forceinline__ unsigned short f2bf(float f) {  // RNE f32->bf16
  unsigned u = __builtin_bit_cast(unsigned, f);
  return (unsigned short)((u + 0x7fffu + ((u >> 16) & 1u)) >> 16);
}
__device__ __forceinline__ float bf2f(unsigned short h) {
  return __builtin_bit_cast(float, ((unsigned)h) << 16);
}
__device__ __forceinline__ float bcl(unsigned u) {  // low bf16 of dword
  return __builtin_bit_cast(float, u << 16);
}
__device__ __forceinline__ float bch(unsigned u) {  // high bf16 of dword
  return __builtin_bit_cast(float, u & 0xffff0000u);
}
// v_rcp_f32 (1 ulp) instead of precise div: error ~1e-7, invisible vs bf16.
__device__ __forceinline__ float sigm(float x) {
  return __builtin_amdgcn_rcpf(1.f + __expf(-x));
}
__device__ __forceinline__ float tanh_f(float x) {
  return 1.f - 2.f * __builtin_amdgcn_rcpf(1.f + __expf(2.f * x));
}

// ---------------------------------------------------------------- prep kernels
__global__ void prep_x(const float* __restrict__ x, unsigned short* __restrict__ xbf) {
  size_t i = ((size_t)blockIdx.x * 256 + threadIdx.x) * 4;  // 8,388,608 elems
  float4 v = *(const float4*)&x[i];
  unsigned long long pk = (unsigned long long)f2bf(v.x)
                        | ((unsigned long long)f2bf(v.y) << 16)
                        | ((unsigned long long)f2bf(v.z) << 32)
                        | ((unsigned long long)f2bf(v.w) << 48);
  *(unsigned long long*)&xbf[i] = pk;
}

// [256,1024] fp32 -> [1024,256] bf16 (works for Wi AND Wh: same shape)
__global__ void prep_wit(const float* __restrict__ W, unsigned short* __restrict__ WT) {
  size_t i = ((size_t)blockIdx.x * 256 + threadIdx.x) * 4;  // 262,144 elems
  float4 v = *(const float4*)&W[i];
  int k = (int)(i >> 10), n = (int)(i & 1023);
  WT[(size_t)(n + 0) * 256 + k] = f2bf(v.x);
  WT[(size_t)(n + 1) * 256 + k] = f2bf(v.y);
  WT[(size_t)(n + 2) * 256 + k] = f2bf(v.z);
  WT[(size_t)(n + 3) * 256 + k] = f2bf(v.w);
}

__global__ void init_hx(unsigned long long* __restrict__ hx) {
  // tag dword := 0xFFFFFFFF (never equals any t in [0,512))
  hx[(size_t)blockIdx.x * 256 + threadIdx.x] = 0xffffffff00000000ULL;
}

// ---------------------------------------------------------------- xg = x@Wi+b
#define XKP 40  // LDS k-pitch (shorts): 80B rows -> 16B-aligned b128, ~2-way banks
__global__ __launch_bounds__(256) void xg_gemm(const unsigned short* __restrict__ xbf,
                                               const unsigned short* __restrict__ WiT,
                                               const float* __restrict__ bias,
                                               unsigned short* __restrict__ xg) {
  __shared__ unsigned short As[128 * XKP];
  __shared__ unsigned short Bs[128 * XKP];
  const int tid = threadIdx.x;
  const int n0 = blockIdx.x * 128, m0 = blockIdx.y * 128;
  const int wave = tid >> 6, lane = tid & 63, quad = lane >> 4, l16 = lane & 15;
  const int wm = wave >> 1, wn = wave & 1;

  float4v acc[4][4];
#pragma unroll
  for (int i = 0; i < 4; ++i)
#pragma unroll
    for (int j = 0; j < 4; ++j) acc[i][j] = (float4v){0.f, 0.f, 0.f, 0.f};

  const int rr = tid >> 2, c8 = (tid & 3) * 8;  // staging coords (16B per thread)
  for (int k0 = 0; k0 < 256; k0 += 32) {
#pragma unroll
    for (int pp = 0; pp < 2; ++pp) {
      int r = pp * 64 + rr;
      *(uint4*)&As[r * XKP + c8] = *(const uint4*)&xbf[(size_t)(m0 + r) * 256 + k0 + c8];
      *(uint4*)&Bs[r * XKP + c8] = *(const uint4*)&WiT[(size_t)(n0 + r) * 256 + k0 + c8];
    }
    __syncthreads();
#pragma unroll
    for (int mt = 0; mt < 4; ++mt) {
      short8 af = *(const short8*)&As[(wm * 64 + mt * 16 + l16) * XKP + quad * 8];
#pragma unroll
      for (int nt = 0; nt < 4; ++nt) {
        short8 bf = *(const short8*)&Bs[(wn * 64 + nt * 16 + l16) * XKP + quad * 8];
        acc[mt][nt] = __builtin_amdgcn_mfma_f32_16x16x32_bf16(af, bf, acc[mt][nt], 0, 0, 0);
      }
    }
    __syncthreads();
  }
  // epilogue: +bias, bf16 store, PERMUTED layout for the scan:
  //   xg[((gate*256 + u)*64 + b)*512 + t]
  // C layout: col=lane&15, row=quad*4+reg. Per lane: r -> consecutive t, so
  // (quad,r,mt) fills 128B-contiguous t-runs per (gate,u) -> L2-merged writes.
#pragma unroll
  for (int nt = 0; nt < 4; ++nt) {
    int col = n0 + wn * 64 + nt * 16 + l16;
    int gate = col >> 8, u = col & 255;
    float bv = bias[col];
#pragma unroll
    for (int mt = 0; mt < 4; ++mt) {
#pragma unroll
      for (int r = 0; r < 4; ++r) {
        int row = m0 + wm * 64 + mt * 16 + quad * 4 + r;
        int b = row >> 9, t = row & 511;
        xg[(((size_t)gate * 256 + u) * 64 + b) * 512 + t] = f2bf(acc[mt][nt][r] + bv);
      }
    }
  }
}

// ---------------------------------------------------------------- LSTM scan
// 8 WGs: bg = wg>>1 (4 batch groups of 16), ug = wg&1 (unit half of 128).
// 512 threads = 8 waves; wave w owns units ug*128 + w*16 .. +16 (x 4 gates).
// Wh B-fragments register-resident: fr[gate][p], p = own-half-first k order.
// hA: double-buffered [2][16 batches][256 k] bf16 in LDS (17 KB).
// hx word layout: [parity][ug][b_glob(64)][word(64)], word j = units 2j,2j+1
// of that half: {lo: u0|u1<<16, hi: tag=t}. 8B agent-scope atomic store is
// single-copy atomic => payload+tag land together; ONE fabric leg per step.
#define HAP 264  // hA pitch (shorts): 528B rows, 16B-aligned b128, ~2-way banks
__global__ __launch_bounds__(512, 2) void lstm_scan(
    const unsigned short* __restrict__ WhT,   // [1024 col][256 k] bf16
    const unsigned short* __restrict__ xgbuf, // [gate][u][b][t] bf16
    unsigned short* __restrict__ hout,
    unsigned long long* __restrict__ hx) {
  __shared__ unsigned short hA[2 * 16 * HAP];
  const int tid = threadIdx.x;
  const int wg = blockIdx.x;                 // 0..7
  const int bg = wg >> 1, ug = wg & 1;
  const int wave = tid >> 6, lane = tid & 63, quad = lane >> 4, l16 = lane & 15;
  const int u_loc = wave * 16 + l16;         // 0..127 within half
  const int u_glob = ug * 128 + u_loc;       // global unit

  // ---- preload Wh B-fragments: fr[g][p] = WhT[g*256+u_glob][kt*32+quad*8..+8]
  // with kt = (ug*4 + p) & 7  => p=0..3 is the OWN k-half, p=4..7 the partner's.
  short8 fr[4][8];
#pragma unroll
  for (int g = 0; g < 4; ++g) {
    const unsigned short* src = WhT + ((size_t)(g * 256 + u_glob)) * 256 + quad * 8;
#pragma unroll
    for (int p = 0; p < 8; ++p) {
      int kt = (ug * 4 + p) & 7;
      fr[g][p] = *(const short8*)&src[kt * 32];
    }
  }
  for (int i = tid; i < 2 * 16 * HAP; i += 512) hA[i] = 0;  // h_{-1} = 0

  const int b0g = bg * 16 + quad * 4;        // first of this lane's 4 batches
  const unsigned short* xgp = xgbuf + ((size_t)u_glob * 64 + b0g) * 512;
  float c[4] = {0.f, 0.f, 0.f, 0.f};         // cell state, register-resident
  unsigned short cx[4][4], nx[4][4];         // xg(t), xg(t+1): [gate][r]
#pragma unroll
  for (int g = 0; g < 4; ++g)
#pragma unroll
    for (int r = 0; r < 4; ++r) cx[g][r] = xgp[(size_t)g * 8388608 + r * 512];

  __syncthreads();

  for (int t = 0; t < 512; ++t) {
    unsigned short* buf = &hA[(t & 1) * 16 * HAP];     // holds h_{t-1}
    float4v acc[4];
#pragma unroll
    for (int g = 0; g < 4; ++g) acc[g] = (float4v){0.f, 0.f, 0.f, 0.f};

    // ---- MFMA over OWN k-half (own h columns, written locally at t-1)
#pragma unroll
    for (int p = 0; p < 4; ++p) {
      int colk = (ug * 128 + p * 32) & 255;            // = kt*32 shorts
      short8 a = *(const short8*)&buf[l16 * HAP + colk + quad * 8];
#pragma unroll
      for (int g = 0; g < 4; ++g)
        acc[g] = __builtin_amdgcn_mfma_f32_16x16x32_bf16(a, fr[g][p], acc[g], 0, 0, 0);
    }

    // ---- prefetch xg(t+1) (L2-resident streams; consumed next iteration)
    int tn = (t < 511) ? t + 1 : t;
#pragma unroll
    for (int g = 0; g < 4; ++g)
#pragma unroll
      for (int r = 0; r < 4; ++r) nx[g][r] = xgp[(size_t)g * 8388608 + r * 512 + tn];

    // ---- poll partner h_{t-1}: words have been in flight since the partner's
    // previous-iteration store => most of the fabric RTT is already hidden.
    if (t > 0) {
      const unsigned tg = (unsigned)(t - 1);
      const unsigned long long* pb =
          hx + (size_t)((t & 1) ^ 1) * 8192 + (size_t)(1 - ug) * 4096 + (size_t)bg * 1024;
      unsigned long long w0, w1;
      int guard = 0;
      bool ok;
      do {
        w0 = __hip_atomic_load(&pb[tid], __ATOMIC_RELAXED, __HIP_MEMORY_SCOPE_AGENT);
        w1 = __hip_atomic_load(&pb[tid + 512], __ATOMIC_RELAXED, __HIP_MEMORY_SCOPE_AGENT);
        ok = ((unsigned)(w0 >> 32) == tg) & ((unsigned)(w1 >> 32) == tg);
      } while (!ok && ++guard < (1 << 20));
      *(unsigned*)&buf[(tid >> 6) * HAP + (1 - ug) * 128 + 2 * (tid & 63)] = (unsigned)w0;
      *(unsigned*)&buf[((tid >> 6) + 8) * HAP + (1 - ug) * 128 + 2 * (tid & 63)] = (unsigned)w1;
    }
    __syncthreads();  // B_mid: partner half of buf complete

    // ---- MFMA over PARTNER k-half
#pragma unroll
    for (int p = 4; p < 8; ++p) {
      int colk = (ug * 128 + p * 32) & 255;
      short8 a = *(const short8*)&buf[l16 * HAP + colk + quad * 8];
#pragma unroll
      for (int g = 0; g < 4; ++g)
        acc[g] = __builtin_amdgcn_mfma_f32_16x16x32_bf16(a, fr[g][p], acc[g], 0, 0, 0);
    }

    // ---- gates, fully in registers: acc[g][r] is gate g of (batch b0g+r, u_glob)
    unsigned hw_[4];
#pragma unroll
    for (int r = 0; r < 4; ++r) {
      float gi = acc[0][r] + bf2f(cx[0][r]);
      float gf = acc[1][r] + bf2f(cx[1][r]);
      float gG = acc[2][r] + bf2f(cx[2][r]);
      float go = acc[3][r] + bf2f(cx[3][r]);
      float cc = sigm(gf) * c[r] + sigm(gi) * tanh_f(gG);
      c[r] = cc;
      hw_[r] = (unsigned)f2bf(sigm(go) * tanh_f(cc));
    }

    // ---- pack pairs (u, u+1) and launch fabric stores FIRST (tag = t)
    unsigned p_[4];
#pragma unroll
    for (int r = 0; r < 4; ++r)
      p_[r] = hw_[r] | ((unsigned)__shfl_down((int)hw_[r], 1) << 16);
    if ((l16 & 1) == 0) {
      const int j = u_loc >> 1;
#pragma unroll
      for (int r = 0; r < 4; ++r) {
        const int bglob = b0g + r;
        unsigned long long val =
            (unsigned long long)p_[r] | ((unsigned long long)(unsigned)t << 32);
        __hip_atomic_store(
            hx + (size_t)(t & 1) * 8192 + (size_t)ug * 4096 + (size_t)bglob * 64 + j,
            val, __ATOMIC_RELAXED, __HIP_MEMORY_SCOPE_AGENT);
        // h history for attention (plain cached store)
        *(unsigned*)&hout[((size_t)bglob * 512 + t) * 256 + u_glob] = p_[r];
      }
    }
    // ---- own h_t -> NEXT buffer (disjoint from buf readers, no extra barrier)
    unsigned short* nbuf = &hA[((t + 1) & 1) * 16 * HAP];
#pragma unroll
    for (int r = 0; r < 4; ++r) nbuf[(quad * 4 + r) * HAP + u_glob] = (unsigned short)hw_[r];

#pragma unroll
    for (int g = 0; g < 4; ++g)
#pragma unroll
      for (int r = 0; r < 4; ++r) cx[g][r] = nx[g][r];
    __syncthreads();  // B_end: own half of next buffer complete
  }
}

// ---------------------------------------------------------------- attention
__global__ __launch_bounds__(256) void attn_qu(const unsigned short* __restrict__ hout,
                                               const float* __restrict__ Wq,
                                               const float* __restrict__ bq,
                                               const float* __restrict__ Wk,
                                               const float* __restrict__ bk,
                                               float* __restrict__ us,
                                               float* __restrict__ cbuf) {
  __shared__ float h0S[256], q0S[256], red[256];
  const int b = blockIdx.x, tid = threadIdx.x;
  h0S[tid] = bf2f(hout[(size_t)b * 512 * 256 + tid]);
  __syncthreads();
  float a = 0.f;
  for (int k = 0; k < 256; ++k) a += h0S[k] * Wq[(size_t)k * 256 + tid];
  q0S[tid] = a + bq[tid];
  __syncthreads();
  red[tid] = q0S[tid] * bk[tid];
  __syncthreads();
  for (int s = 128; s > 0; s >>= 1) {
    if (tid < s) red[tid] += red[tid + s];
    __syncthreads();
  }
  if (tid == 0) cbuf[b] = 0.0625f * red[0];
  // u[d] = scale * dot(Wk row d, q0)
  float acc = 0.f;
  const float* wr = &Wk[(size_t)tid * 256];
  for (int e = 0; e < 256; e += 4) {
    float4 w = *(const float4*)&wr[e];
    acc += w.x * q0S[e] + w.y * q0S[e + 1] + w.z * q0S[e + 2] + w.w * q0S[e + 3];
  }
  us[b * 256 + tid] = 0.0625f * acc;
}

__global__ __launch_bounds__(256) void attn_sm(const unsigned short* __restrict__ hout,
                                               const float* __restrict__ us,
                                               const float* __restrict__ cbuf,
                                               float* __restrict__ hbar) {
  __shared__ float sS[512], red[256], hb4[4][256];
  const int b = blockIdx.x, tid = threadIdx.x, wave = tid >> 6, lane = tid & 63;
  const size_t hb_base = (size_t)b * 512 * 256;
  const float u0 = us[b * 256 + lane * 4 + 0], u1 = us[b * 256 + lane * 4 + 1];
  const float u2 = us[b * 256 + lane * 4 + 2], u3 = us[b * 256 + lane * 4 + 3];
  const float cbv = cbuf[b];
  for (int i = 0; i < 128; ++i) {
    int t = i * 4 + wave;
    unsigned long long hv = *(const unsigned long long*)&hout[hb_base + (size_t)t * 256 + lane * 4];
    unsigned lo = (unsigned)hv, hi = (unsigned)(hv >> 32);
    float p = u0 * bcl(lo) + u1 * bch(lo) + u2 * bcl(hi) + u3 * bch(hi);
    for (int m = 1; m < 64; m <<= 1) p += __shfl_xor(p, m, 64);
    if (lane == 0) sS[t] = p + cbv;
  }
  __syncthreads();
  red[tid] = fmaxf(sS[tid], sS[tid + 256]);
  __syncthreads();
  for (int s = 128; s > 0; s >>= 1) {
    if (tid < s) red[tid] = fmaxf(red[tid], red[tid + s]);
    __syncthreads();
  }
  float mx = red[0];
  __syncthreads();
  float e0 = __expf(sS[tid] - mx), e1 = __expf(sS[tid + 256] - mx);
  sS[tid] = e0; sS[tid + 256] = e1;
  red[tid] = e0 + e1;
  __syncthreads();
  for (int s = 128; s > 0; s >>= 1) {
    if (tid < s) red[tid] += red[tid + s];
    __syncthreads();
  }
  float inv = 1.f / red[0];
  // hbar[d] = (sum_t e[t]*h[t,d]) * inv  — per-wave partials over t
  float a0 = 0.f, a1 = 0.f, a2 = 0.f, a3 = 0.f;
  const int d0 = lane * 4;
  for (int i = 0; i < 128; ++i) {
    int t = wave * 128 + i;
    float w = sS[t];
    unsigned long long hv = *(const unsigned long long*)&hout[hb_base + (size_t)t * 256 + d0];
    unsigned lo = (unsigned)hv, hi = (unsigned)(hv >> 32);
    a0 += w * bcl(lo); a1 += w * bch(lo); a2 += w * bcl(hi); a3 += w * bch(hi);
  }
  hb4[wave][d0] = a0; hb4[wave][d0 + 1] = a1; hb4[wave][d0 + 2] = a2; hb4[wave][d0 + 3] = a3;
  __syncthreads();
  hbar[b * 256 + tid] = (hb4[0][tid] + hb4[1][tid] + hb4[2][tid] + hb4[3][tid]) * inv;
}

// ---------------------------------------------------------------- MLP head
__global__ __launch_bounds__(256) void head_k(const float* __restrict__ hbar,
                                              const float* __restrict__ Wv, const float* __restrict__ bv,
                                              const float* __restrict__ Wo, const float* __restrict__ bo,
                                              const float* __restrict__ W1, const float* __restrict__ b1,
                                              const float* __restrict__ W2, const float* __restrict__ b2,
                                              float* __restrict__ out) {
  __shared__ float hS[256], oS[256], o1S[256], zS[32];
  const int b = blockIdx.x, tid = threadIdx.x;
  hS[tid] = hbar[b * 256 + tid];
  __syncthreads();
  float a = 0.f;
  for (int k = 0; k < 256; ++k) a += hS[k] * Wv[(size_t)k * 256 + tid];
  oS[tid] = a + bv[tid];
  __syncthreads();
  a = 0.f;
  for (int k = 0; k < 256; ++k) a += oS[k] * Wo[(size_t)k * 256 + tid];
  o1S[tid] = a + bo[tid];
  __syncthreads();
  if (tid < 32) {
    a = 0.f;
    for (int k = 0; k < 256; ++k) a += o1S[k] * W1[k * 32 + tid];
    zS[tid] = fmaxf(a + b1[tid], 0.f);
  }
  __syncthreads();
  if (tid < 3) {
    a = 0.f;
    for (int j = 0; j < 32; ++j) a += zS[j] * W2[j * 3 + tid];
    out[b * 3 + tid] = a + b2[tid];
  }
}

// ---------------------------------------------------------------- launch
extern "C" void kernel_launch(void* const* d_in, const int* in_sizes, int n_in,
                              void* d_out, int out_size, void* d_ws, size_t ws_size,
                              hipStream_t stream) {
  const float* x  = (const float*)d_in[0];
  const float* Wi = (const float*)d_in[1];
  const float* Wh = (const float*)d_in[2];
  const float* bG = (const float*)d_in[3];
  const float* Wq = (const float*)d_in[4];
  const float* bq = (const float*)d_in[5];
  const float* Wk = (const float*)d_in[6];
  const float* bk = (const float*)d_in[7];
  const float* Wv = (const float*)d_in[8];
  const float* bv = (const float*)d_in[9];
  const float* Wo = (const float*)d_in[10];
  const float* bo = (const float*)d_in[11];
  const float* W1 = (const float*)d_in[12];
  const float* b1 = (const float*)d_in[13];
  const float* W2 = (const float*)d_in[14];
  const float* b2 = (const float*)d_in[15];
  float* out = (float*)d_out;
  char* ws = (char*)d_ws;

  unsigned short* xg    = (unsigned short*)(ws);              // 67,108,864 B
  unsigned short* hout  = (unsigned short*)(ws + 67108864);   // 16,777,216 B
  unsigned short* xbf   = (unsigned short*)(ws + 83886080);   // 16,777,216 B (dead after xg_gemm)
  unsigned short* WhT   = (unsigned short*)(ws + 83886080);   //    524,288 B (reuses xbf region)
  unsigned short* WiT   = (unsigned short*)(ws + 100663296);  //    524,288 B
  unsigned long long* hx = (unsigned long long*)(ws + 101187584);  // 131,072 B
  float*          us    = (float*)(ws + 101318656);           //     65,536 B
  float*          cbuf  = (float*)(ws + 101384192);           //      1,024 B
  float*          hbar  = (float*)(ws + 101385216);           //     65,536 B
  // total ~101.5 MB of workspace (unchanged)

  prep_x<<<dim3(8192), dim3(256), 0, stream>>>(x, xbf);
  prep_wit<<<dim3(256), dim3(256), 0, stream>>>(Wi, WiT);
  init_hx<<<dim3(64), dim3(256), 0, stream>>>(hx);
  xg_gemm<<<dim3(8, 256), dim3(256), 0, stream>>>(xbf, WiT, bG, xg);
  // xbf is dead now; transpose/bf16-cast Wh into its region (stream-ordered)
  prep_wit<<<dim3(256), dim3(256), 0, stream>>>(Wh, WhT);
  lstm_scan<<<dim3(8), dim3(512), 0, stream>>>(WhT, xg, hout, hx);
  attn_qu<<<dim3(64), dim3(256), 0, stream>>>(hout, Wq, bq, Wk, bk, us, cbuf);
  attn_sm<<<dim3(64), dim3(256), 0, stream>>>(hout, us, cbuf, hbar);
  head_k<<<dim3(64), dim3(256), 0, stream>>>(hbar, Wv, bv, Wo, bo, W1, b1, W2, b2, out);
}

// Round 2
// 1351.986 us; speedup vs baseline: 2.4706x; 2.4706x over previous
//
#include <hip/hip_runtime.h>
#include <hip/hip_bf16.h>

// ---------------------------------------------------------------------------
// myLSTM R2: exchange-free LSTM scan.
//   prep_all  : x->bf16 ; Wi -> WiT [1024][256] bf16 ; Wh -> WhP permuted
//               [1024][256] bf16 with row' = w*128+rt*16+q*4+r  <->
//               (gate=r, unit=w*32+rt*4+q)  so MFMA acc is gate-aligned.
//   xg_gemm   : xg = x@Wi + b  (bf16 MFMA 128x128 tiles), written PERMUTED
//               as [b][t][u][gate] so the scan loads 4 gates as one 8B word.
//   lstm_scan : 64 WGs, one per batch. NO inter-WG traffic at all.
//               512 thr (8 waves, 2/SIMD). Whole Wh resident per CU:
//               6 row-tiles/wave in VGPR/AGPR A-fragments (192 regs),
//               2 row-tiles/wave in LDS (131 KB, XOR-swizzled rows).
//               h_{t-1} = 512B in LDS, consumed as BROADCAST B-fragment
//               (same 16B for all l16 -> conflict-free; C cols duplicated,
//               so lane (quad,l16<8) directly owns the 4 gates of unit
//               u = w*32 + l16*4 + quad in acc[l16][0..3]).
//               Per step: 8x{bcast h read + 6 reg-MFMA + 2 LDS-MFMA}
//               -> barrier -> gates in-register -> write h (512B) + hout
//               -> barrier.  ~1900 cy/step, deterministic.
//   attn_head : fused attn_qu + attn_sm + MLP head (block-local per batch).
// ---------------------------------------------------------------------------

typedef __attribute__((ext_vector_type(8))) short short8;   // 8 x bf16 (4 VGPR)
typedef __attribute__((ext_vector_type(4))) float float4v;  // MFMA acc

__device__ __forceinline__ unsigned short f2bf(float f) {  // RNE f32->bf16
  unsigned u = __builtin_bit_cast(unsigned, f);
  return (unsigned short)((u + 0x7fffu + ((u >> 16) & 1u)) >> 16);
}
__device__ __forceinline__ float bf2f(unsigned short h) {
  return __builtin_bit_cast(float, ((unsigned)h) << 16);
}
__device__ __forceinline__ float bcl(unsigned u) {  // low bf16 of dword
  return __builtin_bit_cast(float, u << 16);
}
__device__ __forceinline__ float bch(unsigned u) {  // high bf16 of dword
  return __builtin_bit_cast(float, u & 0xffff0000u);
}
// v_rcp_f32 (1 ulp) instead of precise div: error ~1e-7, invisible vs bf16.
__device__ __forceinline__ float sigm(float x) {
  return __builtin_amdgcn_rcpf(1.f + __expf(-x));
}
__device__ __forceinline__ float tanh_f(float x) {
  return 1.f - 2.f * __builtin_amdgcn_rcpf(1.f + __expf(2.f * x));
}

// ---------------------------------------------------------------- prep (fused)
// blocks [0,8192)    : x fp32 -> bf16                (8,388,608 elems)
// blocks [8192,8448) : Wi [256,1024] -> WiT [1024][256] bf16
// blocks [8448,8704) : Wh [256,1024] -> WhP [1024][256] bf16, row-permuted
__global__ void prep_all(const float* __restrict__ x,
                         const float* __restrict__ Wi,
                         const float* __restrict__ Wh,
                         unsigned short* __restrict__ xbf,
                         unsigned short* __restrict__ WiT,
                         unsigned short* __restrict__ WhP) {
  const int bid = blockIdx.x, tid = threadIdx.x;
  if (bid < 8192) {
    size_t i = ((size_t)bid * 256 + tid) * 4;
    float4 v = *(const float4*)&x[i];
    unsigned long long pk = (unsigned long long)f2bf(v.x)
                          | ((unsigned long long)f2bf(v.y) << 16)
                          | ((unsigned long long)f2bf(v.z) << 32)
                          | ((unsigned long long)f2bf(v.w) << 48);
    *(unsigned long long*)&xbf[i] = pk;
  } else if (bid < 8448) {
    size_t i = ((size_t)(bid - 8192) * 256 + tid) * 4;
    float4 v = *(const float4*)&Wi[i];
    int k = (int)(i >> 10), n = (int)(i & 1023);
    WiT[(size_t)(n + 0) * 256 + k] = f2bf(v.x);
    WiT[(size_t)(n + 1) * 256 + k] = f2bf(v.y);
    WiT[(size_t)(n + 2) * 256 + k] = f2bf(v.z);
    WiT[(size_t)(n + 3) * 256 + k] = f2bf(v.w);
  } else {
    size_t i0 = ((size_t)(bid - 8448) * 256 + tid) * 4;
    int row = (int)(i0 >> 8);  // same row for all 4 (i0 % 256 <= 252)
    // row' = w*128 + rt*16 + q*4 + r  ->  col_nat = r*256 + w*32 + rt*4 + q
    int colnat = (row & 3) * 256 + (row >> 7) * 32 + ((row >> 4) & 7) * 4 +
                 ((row >> 2) & 3);
    unsigned long long pk = 0;
#pragma unroll
    for (int j = 0; j < 4; ++j) {
      int k = (int)((i0 + j) & 255);
      pk |= (unsigned long long)f2bf(Wh[(size_t)k * 1024 + colnat]) << (16 * j);
    }
    *(unsigned long long*)&WhP[i0] = pk;
  }
}

// ---------------------------------------------------------------- xg = x@Wi+b
#define XKP 40  // LDS k-pitch (shorts): 80B rows -> 16B-aligned b128, ~2-way banks
__global__ __launch_bounds__(256) void xg_gemm(const unsigned short* __restrict__ xbf,
                                               const unsigned short* __restrict__ WiT,
                                               const float* __restrict__ bias,
                                               unsigned short* __restrict__ xg) {
  __shared__ unsigned short As[128 * XKP];
  __shared__ unsigned short Bs[128 * XKP];
  const int tid = threadIdx.x;
  const int n0 = blockIdx.x * 128, m0 = blockIdx.y * 128;
  const int wave = tid >> 6, lane = tid & 63, quad = lane >> 4, l16 = lane & 15;
  const int wm = wave >> 1, wn = wave & 1;

  float4v acc[4][4];
#pragma unroll
  for (int i = 0; i < 4; ++i)
#pragma unroll
    for (int j = 0; j < 4; ++j) acc[i][j] = (float4v){0.f, 0.f, 0.f, 0.f};

  const int rr = tid >> 2, c8 = (tid & 3) * 8;  // staging coords (16B per thread)
  for (int k0 = 0; k0 < 256; k0 += 32) {
#pragma unroll
    for (int pp = 0; pp < 2; ++pp) {
      int r = pp * 64 + rr;
      *(uint4*)&As[r * XKP + c8] = *(const uint4*)&xbf[(size_t)(m0 + r) * 256 + k0 + c8];
      *(uint4*)&Bs[r * XKP + c8] = *(const uint4*)&WiT[(size_t)(n0 + r) * 256 + k0 + c8];
    }
    __syncthreads();
#pragma unroll
    for (int mt = 0; mt < 4; ++mt) {
      short8 af = *(const short8*)&As[(wm * 64 + mt * 16 + l16) * XKP + quad * 8];
#pragma unroll
      for (int nt = 0; nt < 4; ++nt) {
        short8 bf = *(const short8*)&Bs[(wn * 64 + nt * 16 + l16) * XKP + quad * 8];
        acc[mt][nt] = __builtin_amdgcn_mfma_f32_16x16x32_bf16(af, bf, acc[mt][nt], 0, 0, 0);
      }
    }
    __syncthreads();
  }
  // epilogue: +bias, bf16 store, PERMUTED layout for the scan:
  //   xg[((b*512 + t)*256 + u)*4 + gate]   (4 gates of a unit contiguous, 8B)
#pragma unroll
  for (int nt = 0; nt < 4; ++nt) {
    int col = n0 + wn * 64 + nt * 16 + l16;
    int gate = col >> 8, u = col & 255;
    float bv = bias[col];
#pragma unroll
    for (int mt = 0; mt < 4; ++mt) {
#pragma unroll
      for (int r = 0; r < 4; ++r) {
        int row = m0 + wm * 64 + mt * 16 + quad * 4 + r;
        int b = row >> 9, t = row & 511;
        xg[(((size_t)b * 512 + t) * 256 + u) * 4 + gate] = f2bf(acc[mt][nt][r] + bv);
      }
    }
  }
}

// ---------------------------------------------------------------- LSTM scan
// 64 WGs, one batch each. 512 threads = 8 waves, 2 waves/SIMD, <=256 VGPR.
// Wave w owns Wh rows [w*128, (w+1)*128): tiles rt=0..5 in registers,
// rt=6,7 in LDS (swizzled). h_{t-1} (256 bf16, 512B) broadcast from LDS.
#define SWZ(rowv, off) ((off) ^ (((rowv) & 7) << 4))
__global__ __launch_bounds__(512, 2) void lstm_scan(
    const unsigned short* __restrict__ WhP,  // [1024][256] bf16 (permuted rows)
    const unsigned short* __restrict__ xg,   // [b][t][u][gate] bf16
    unsigned short* __restrict__ hout) {
  __shared__ unsigned short WhL[16 * 16 * 256];  // 16 tiles x 16 rows x 512B = 131072B
  __shared__ unsigned short hA[256];             // h_{t-1}, 512 B
  const int tid = threadIdx.x;
  const int b = blockIdx.x;  // batch
  const int wave = tid >> 6, lane = tid & 63, quad = lane >> 4, l16 = lane & 15;

  // ---- preload 6 register tiles: frA[rt][kt] = WhP[w*128+rt*16+l16][kt*32+quad*8..]
  short8 frA[6][8];
  {
    const unsigned short* src = WhP + ((size_t)(wave * 128) + l16) * 256 + quad * 8;
#pragma unroll
    for (int rt = 0; rt < 6; ++rt)
#pragma unroll
      for (int kt = 0; kt < 8; ++kt)
        frA[rt][kt] = *(const short8*)&src[(size_t)rt * 4096 + kt * 32];
  }
  // ---- stage LDS tiles (rows 96..127 of this wave's slice), swizzled
  for (int it = 0; it < 16; ++it) {
    int idx = it * 64 + lane;            // 1024 16B-chunks per wave
    int r32 = idx >> 5, ch = idx & 31;   // row 0..31, chunk 0..31
    int tile = wave * 2 + (r32 >> 4), rw = r32 & 15;
    uint4 v = *(const uint4*)&WhP[((size_t)wave * 128 + 96 + r32) * 256 + ch * 8];
    *(uint4*)((char*)WhL + tile * 8192 + rw * 512 + SWZ(rw, ch * 16)) = v;
  }
  for (int i = tid; i < 256; i += 512) hA[i] = 0;  // h_{-1} = 0
  __syncthreads();

  const bool act = (l16 < 8);                  // gate-owning lanes (32/wave)
  const int u = wave * 32 + l16 * 4 + quad;    // this lane's unit (if act)
  const unsigned short* xgp = xg + ((size_t)b * 512 * 256 + u) * 4;
  unsigned short* houtp = hout + (size_t)b * 512 * 256 + u;
  float c = 0.f;

  const char* ldsA = (const char*)WhL + (wave * 2) * 8192 + l16 * 512;
  const char* ldsB = ldsA + 8192;

  for (int t = 0; t < 512; ++t) {
    // xg(t): 4 gates of this lane's unit, one 8B load, issued early
    unsigned long long xv = 0;
    if (act) xv = *(const unsigned long long*)&xgp[(size_t)t * 1024];

    float4v acc[8];
#pragma unroll
    for (int rt = 0; rt < 8; ++rt) acc[rt] = (float4v){0.f, 0.f, 0.f, 0.f};

#pragma unroll
    for (int kt = 0; kt < 8; ++kt) {
      // broadcast h chunk: same 16B for all l16 of a quad -> conflict-free
      short8 hb = *(const short8*)((const char*)hA + kt * 64 + quad * 16);
#pragma unroll
      for (int rt = 0; rt < 6; ++rt)
        acc[rt] = __builtin_amdgcn_mfma_f32_16x16x32_bf16(frA[rt][kt], hb, acc[rt], 0, 0, 0);
      short8 a6 = *(const short8*)(ldsA + SWZ(l16, kt * 64 + quad * 16));
      acc[6] = __builtin_amdgcn_mfma_f32_16x16x32_bf16(a6, hb, acc[6], 0, 0, 0);
      short8 a7 = *(const short8*)(ldsB + SWZ(l16, kt * 64 + quad * 16));
      acc[7] = __builtin_amdgcn_mfma_f32_16x16x32_bf16(a7, hb, acc[7], 0, 0, 0);
    }
    __syncthreads();  // all hA reads complete before overwrite

    if (act) {
      // select this lane's tile: rt == l16 (static unroll -> cndmask chain)
      float4v g4 = acc[0];
#pragma unroll
      for (int rt = 1; rt < 8; ++rt)
        if (l16 == rt) g4 = acc[rt];
      // acc[rt][r]: r = gate (i,f,g,o) of unit u  (row' = ..+quad*4+r)
      float gi = g4[0] + bf2f((unsigned short)(xv));
      float gf = g4[1] + bf2f((unsigned short)(xv >> 16));
      float gG = g4[2] + bf2f((unsigned short)(xv >> 32));
      float go = g4[3] + bf2f((unsigned short)(xv >> 48));
      float cc = sigm(gf) * c + sigm(gi) * tanh_f(gG);
      c = cc;
      unsigned short hb16 = f2bf(sigm(go) * tanh_f(cc));
      hA[u] = hb16;                       // 512B total, conflict-free
      houtp[(size_t)t * 256] = hb16;      // h history for attention
    }
    __syncthreads();  // h_t visible for next step
  }
}

// --------------------------------------------------- attention + head (fused)
__global__ __launch_bounds__(256) void attn_head(
    const unsigned short* __restrict__ hout,
    const float* __restrict__ Wq, const float* __restrict__ bq,
    const float* __restrict__ Wk, const float* __restrict__ bk,
    const float* __restrict__ Wv, const float* __restrict__ bv,
    const float* __restrict__ Wo, const float* __restrict__ bo,
    const float* __restrict__ W1, const float* __restrict__ b1,
    const float* __restrict__ W2, const float* __restrict__ b2,
    float* __restrict__ out) {
  __shared__ float h0S[256], q0S[256], red[256], usS[256], sS[512], hb4[4][256];
  __shared__ float oS[256], o1S[256], zS[32], cbS;
  const int b = blockIdx.x, tid = threadIdx.x, wave = tid >> 6, lane = tid & 63;
  const size_t hb_base = (size_t)b * 512 * 256;

  // ---- q0 = h0@Wq+bq ; u = Wk@(scale*q0) ; cb = scale*q0.bk
  h0S[tid] = bf2f(hout[hb_base + tid]);
  __syncthreads();
  float a = 0.f;
  for (int k = 0; k < 256; ++k) a += h0S[k] * Wq[(size_t)k * 256 + tid];
  q0S[tid] = a + bq[tid];
  __syncthreads();
  red[tid] = q0S[tid] * bk[tid];
  __syncthreads();
  for (int s = 128; s > 0; s >>= 1) {
    if (tid < s) red[tid] += red[tid + s];
    __syncthreads();
  }
  if (tid == 0) cbS = 0.0625f * red[0];
  float acq = 0.f;
  const float* wr = &Wk[(size_t)tid * 256];
  for (int e = 0; e < 256; e += 4) {
    float4 w = *(const float4*)&wr[e];
    acq += w.x * q0S[e] + w.y * q0S[e + 1] + w.z * q0S[e + 2] + w.w * q0S[e + 3];
  }
  usS[tid] = 0.0625f * acq;
  __syncthreads();

  // ---- scores = u.h[b,t]+cb -> softmax -> hbar = sum attn*h
  const float u0 = usS[lane * 4 + 0], u1 = usS[lane * 4 + 1];
  const float u2 = usS[lane * 4 + 2], u3 = usS[lane * 4 + 3];
  const float cbv = cbS;
  for (int i = 0; i < 128; ++i) {
    int t = i * 4 + wave;
    unsigned long long hv = *(const unsigned long long*)&hout[hb_base + (size_t)t * 256 + lane * 4];
    unsigned lo = (unsigned)hv, hi = (unsigned)(hv >> 32);
    float p = u0 * bcl(lo) + u1 * bch(lo) + u2 * bcl(hi) + u3 * bch(hi);
    for (int m = 1; m < 64; m <<= 1) p += __shfl_xor(p, m, 64);
    if (lane == 0) sS[t] = p + cbv;
  }
  __syncthreads();
  red[tid] = fmaxf(sS[tid], sS[tid + 256]);
  __syncthreads();
  for (int s = 128; s > 0; s >>= 1) {
    if (tid < s) red[tid] = fmaxf(red[tid], red[tid + s]);
    __syncthreads();
  }
  float mx = red[0];
  __syncthreads();
  float e0 = __expf(sS[tid] - mx), e1 = __expf(sS[tid + 256] - mx);
  sS[tid] = e0; sS[tid + 256] = e1;
  red[tid] = e0 + e1;
  __syncthreads();
  for (int s = 128; s > 0; s >>= 1) {
    if (tid < s) red[tid] += red[tid + s];
    __syncthreads();
  }
  float inv = 1.f / red[0];
  float a0 = 0.f, a1 = 0.f, a2 = 0.f, a3 = 0.f;
  const int d0 = lane * 4;
  for (int i = 0; i < 128; ++i) {
    int t = wave * 128 + i;
    float w = sS[t];
    unsigned long long hv = *(const unsigned long long*)&hout[hb_base + (size_t)t * 256 + d0];
    unsigned lo = (unsigned)hv, hi = (unsigned)(hv >> 32);
    a0 += w * bcl(lo); a1 += w * bch(lo); a2 += w * bcl(hi); a3 += w * bch(hi);
  }
  hb4[wave][d0] = a0; hb4[wave][d0 + 1] = a1; hb4[wave][d0 + 2] = a2; hb4[wave][d0 + 3] = a3;
  __syncthreads();
  h0S[tid] = (hb4[0][tid] + hb4[1][tid] + hb4[2][tid] + hb4[3][tid]) * inv;  // hbar
  __syncthreads();

  // ---- head: o0=hbar@Wv+bv ; o1=o0@Wo+bo ; z=relu(o1@W1+b1) ; out=z@W2+b2
  a = 0.f;
  for (int k = 0; k < 256; ++k) a += h0S[k] * Wv[(size_t)k * 256 + tid];
  oS[tid] = a + bv[tid];
  __syncthreads();
  a = 0.f;
  for (int k = 0; k < 256; ++k) a += oS[k] * Wo[(size_t)k * 256 + tid];
  o1S[tid] = a + bo[tid];
  __syncthreads();
  if (tid < 32) {
    a = 0.f;
    for (int k = 0; k < 256; ++k) a += o1S[k] * W1[k * 32 + tid];
    zS[tid] = fmaxf(a + b1[tid], 0.f);
  }
  __syncthreads();
  if (tid < 3) {
    a = 0.f;
    for (int j = 0; j < 32; ++j) a += zS[j] * W2[j * 3 + tid];
    out[b * 3 + tid] = a + b2[tid];
  }
}

// ---------------------------------------------------------------- launch
extern "C" void kernel_launch(void* const* d_in, const int* in_sizes, int n_in,
                              void* d_out, int out_size, void* d_ws, size_t ws_size,
                              hipStream_t stream) {
  const float* x  = (const float*)d_in[0];
  const float* Wi = (const float*)d_in[1];
  const float* Wh = (const float*)d_in[2];
  const float* bG = (const float*)d_in[3];
  const float* Wq = (const float*)d_in[4];
  const float* bq = (const float*)d_in[5];
  const float* Wk = (const float*)d_in[6];
  const float* bk = (const float*)d_in[7];
  const float* Wv = (const float*)d_in[8];
  const float* bv = (const float*)d_in[9];
  const float* Wo = (const float*)d_in[10];
  const float* bo = (const float*)d_in[11];
  const float* W1 = (const float*)d_in[12];
  const float* b1 = (const float*)d_in[13];
  const float* W2 = (const float*)d_in[14];
  const float* b2 = (const float*)d_in[15];
  float* out = (float*)d_out;
  char* ws = (char*)d_ws;

  unsigned short* xg   = (unsigned short*)(ws);              // 67,108,864 B
  unsigned short* hout = (unsigned short*)(ws + 67108864);   // 16,777,216 B
  unsigned short* xbf  = (unsigned short*)(ws + 83886080);   // 16,777,216 B
  unsigned short* WiT  = (unsigned short*)(ws + 100663296);  //    524,288 B
  unsigned short* WhP  = (unsigned short*)(ws + 101187584);  //    524,288 B
  // total ~101.7 MB of workspace

  prep_all<<<dim3(8704), dim3(256), 0, stream>>>(x, Wi, Wh, xbf, WiT, WhP);
  xg_gemm<<<dim3(8, 256), dim3(256), 0, stream>>>(xbf, WiT, bG, xg);
  lstm_scan<<<dim3(64), dim3(512), 0, stream>>>(WhP, xg, hout);
  attn_head<<<dim3(64), dim3(256), 0, stream>>>(hout, Wq, bq, Wk, bk, Wv, bv,
                                                Wo, bo, W1, b1, W2, b2, out);
}